// Round 1
// baseline (61.610 us; speedup 1.0000x reference)
//
#include <hip/hip_runtime.h>

#define SCALE 0.0625f
#define P_OUT 28
#define R_N 128
#define C_N 256
#define HF 50
#define WF 76

// One block per (roi, channel) plane. Computes a full 28x28 output tile.
__global__ __launch_bounds__(256) void roi_adaptive_pool_kernel(
    const float* __restrict__ input,   // [N, C, HF, WF]
    const float* __restrict__ rois,    // [R, 5] = (batch_idx, x1, y1, x2, y2)
    float* __restrict__ out)           // [R, C, P, P]
{
    __shared__ int ys[P_OUT], ye[P_OUT], xs[P_OUT], xe[P_OUT];
    __shared__ float icy[P_OUT], icx[P_OUT];
    __shared__ int s_idx;

    const int blk = blockIdx.x;
    const int c = blk & (C_N - 1);   // C_N = 256 (power of 2)
    const int r = blk >> 8;
    const int tid = threadIdx.x;

    if (tid == 0) {
        s_idx = (int)rois[r * 5 + 0];
    }
    if (tid < P_OUT) {
        // y (row) bins — replicate reference exactly
        const float lo_img = rois[r * 5 + 2];
        const float hi_img = rois[r * 5 + 4];
        int lo = (int)floorf(SCALE * lo_img - 0.5f);
        if (lo < 0) lo = 0;
        int hi = (int)ceilf(SCALE * hi_img - 0.5f);
        if (hi == lo) hi += 1;
        if (hi > HF) hi = HF;
        const int len = hi - lo;
        const int i = tid;
        const int st = lo + (i * len) / P_OUT;                    // floor
        const int en = lo + ((i + 1) * len + P_OUT - 1) / P_OUT;  // ceil
        ys[i] = st;
        ye[i] = en;
        icy[i] = 1.0f / (float)(en - st);
    } else if (tid >= 64 && tid < 64 + P_OUT) {
        // x (col) bins — second wave, runs in parallel with y-bin wave
        const float lo_img = rois[r * 5 + 1];
        const float hi_img = rois[r * 5 + 3];
        int lo = (int)floorf(SCALE * lo_img - 0.5f);
        if (lo < 0) lo = 0;
        int hi = (int)ceilf(SCALE * hi_img - 0.5f);
        if (hi == lo) hi += 1;
        if (hi > WF) hi = WF;
        const int len = hi - lo;
        const int i = tid - 64;
        const int st = lo + (i * len) / P_OUT;
        const int en = lo + ((i + 1) * len + P_OUT - 1) / P_OUT;
        xs[i] = st;
        xe[i] = en;
        icx[i] = 1.0f / (float)(en - st);
    }
    __syncthreads();

    const float* __restrict__ base =
        input + ((size_t)s_idx * C_N + c) * (size_t)(HF * WF);
    float* __restrict__ obase =
        out + ((size_t)r * C_N + c) * (size_t)(P_OUT * P_OUT);

    // 784 outputs per block, 256 threads -> up to 4 per thread.
    // Consecutive threads write consecutive addresses (coalesced).
    for (int t = tid; t < P_OUT * P_OUT; t += 256) {
        const int q = t % P_OUT;
        const int p = t / P_OUT;
        const int y0 = ys[p], y1v = ye[p];
        const int x0 = xs[q], x1v = xe[q];
        float s = 0.0f;
        for (int h = y0; h < y1v; ++h) {
            const float* __restrict__ row = base + h * WF;
            for (int w = x0; w < x1v; ++w) {
                s += row[w];
            }
        }
        obase[t] = s * icy[p] * icx[q];
    }
}

extern "C" void kernel_launch(void* const* d_in, const int* in_sizes, int n_in,
                              void* d_out, int out_size, void* d_ws, size_t ws_size,
                              hipStream_t stream) {
    const float* input = (const float*)d_in[0];  // [4,256,50,76]
    const float* rois  = (const float*)d_in[1];  // [128,5]
    float* out = (float*)d_out;                  // [128,256,28,28]

    const int grid = R_N * C_N;  // 32768 blocks, one per (r,c) plane
    roi_adaptive_pool_kernel<<<grid, 256, 0, stream>>>(input, rois, out);
}

// Round 3
// 50.690 us; speedup vs baseline: 1.2154x; 1.2154x over previous
//
#include <hip/hip_runtime.h>

#define SCALE 0.0625f
#define P_OUT 28
#define R_N 128
#define C_N 256
#define HF 50
#define WF 76
#define HW (HF * WF)
#define CPB 16   // channels per block

typedef float f32x4 __attribute__((ext_vector_type(4)));

// One block per (roi, 16-channel chunk). Each thread owns a fixed
// (p, q0..q0+3) output quad and iterates channels -> float4 stores,
// all bin math hoisted out of the channel loop.
__global__ __launch_bounds__(256) void roi_pool_kernel(
    const float* __restrict__ input,   // [N, C, HF, WF]
    const float* __restrict__ rois,    // [R, 5]
    float* __restrict__ out)           // [R, C, P, P]
{
    __shared__ int ysS[P_OUT], yeS[P_OUT], xsS[P_OUT], xeS[P_OUT];
    __shared__ float icyS[P_OUT], icxS[P_OUT];
    __shared__ int s_idx;

    const int bid = blockIdx.x;
    const int r   = bid >> 4;           // bid / 16
    const int c0  = (bid & 15) * CPB;
    const int tid = threadIdx.x;

    if (tid == 0) s_idx = (int)rois[r * 5 + 0];
    if (tid < P_OUT) {
        // y (row) bins — exact reference integer math
        const float lo_img = rois[r * 5 + 2];
        const float hi_img = rois[r * 5 + 4];
        int lo = (int)floorf(SCALE * lo_img - 0.5f);
        if (lo < 0) lo = 0;
        int hi = (int)ceilf(SCALE * hi_img - 0.5f);
        if (hi == lo) hi += 1;
        if (hi > HF) hi = HF;
        const int len = hi - lo;
        const int st = lo + (tid * len) / P_OUT;
        const int en = lo + ((tid + 1) * len + P_OUT - 1) / P_OUT;
        ysS[tid] = st; yeS[tid] = en;
        icyS[tid] = 1.0f / (float)(en - st);
    } else if (tid >= 64 && tid < 64 + P_OUT) {
        // x (col) bins — second wave in parallel
        const int i = tid - 64;
        const float lo_img = rois[r * 5 + 1];
        const float hi_img = rois[r * 5 + 3];
        int lo = (int)floorf(SCALE * lo_img - 0.5f);
        if (lo < 0) lo = 0;
        int hi = (int)ceilf(SCALE * hi_img - 0.5f);
        if (hi == lo) hi += 1;
        if (hi > WF) hi = WF;
        const int len = hi - lo;
        const int st = lo + (i * len) / P_OUT;
        const int en = lo + ((i + 1) * len + P_OUT - 1) / P_OUT;
        xsS[i] = st; xeS[i] = en;
        icxS[i] = 1.0f / (float)(en - st);
    }
    __syncthreads();

    if (tid >= 196) return;   // 196 quads of 4 cover the 784 outputs

    // Fixed output position for this thread: t0 = 4*tid, p = t0/28, q0 = t0%28.
    // 28 % 4 == 0 -> a quad never crosses a p-row.
    const int p  = tid / 7;
    const int q0 = (tid % 7) * 4;

    const int y0 = ysS[p], y1 = yeS[p];
    const float cy = icyS[p];
    const int xs0 = xsS[q0 + 0], xe0 = xeS[q0 + 0];
    const int xs1 = xsS[q0 + 1], xe1 = xeS[q0 + 1];
    const int xs2 = xsS[q0 + 2], xe2 = xeS[q0 + 2];
    const int xs3 = xsS[q0 + 3], xe3 = xeS[q0 + 3];
    const float w0 = cy * icxS[q0 + 0];
    const float w1 = cy * icxS[q0 + 1];
    const float w2 = cy * icxS[q0 + 2];
    const float w3 = cy * icxS[q0 + 3];

    const float* __restrict__ base =
        input + ((size_t)s_idx * C_N + c0) * (size_t)HW;
    float* __restrict__ ob =
        out + ((size_t)r * C_N + c0) * (size_t)(P_OUT * P_OUT) + tid * 4;

    for (int c = 0; c < CPB; ++c) {
        float s0 = 0.f, s1 = 0.f, s2 = 0.f, s3 = 0.f;
        for (int h = y0; h < y1; ++h) {
            const float* __restrict__ row = base + h * WF;
            for (int w = xs0; w < xe0; ++w) s0 += row[w];
            for (int w = xs1; w < xe1; ++w) s1 += row[w];
            for (int w = xs2; w < xe2; ++w) s2 += row[w];
            for (int w = xs3; w < xe3; ++w) s3 += row[w];
        }
        f32x4 v;
        v.x = s0 * w0; v.y = s1 * w1; v.z = s2 * w2; v.w = s3 * w3;
        __builtin_nontemporal_store(v, (f32x4*)ob);
        base += HW;                // next channel plane
        ob   += P_OUT * P_OUT;
    }
}

extern "C" void kernel_launch(void* const* d_in, const int* in_sizes, int n_in,
                              void* d_out, int out_size, void* d_ws, size_t ws_size,
                              hipStream_t stream) {
    const float* input = (const float*)d_in[0];  // [4,256,50,76]
    const float* rois  = (const float*)d_in[1];  // [128,5]
    float* out = (float*)d_out;                  // [128,256,28,28]

    const int grid = R_N * (C_N / CPB);          // 128 * 16 = 2048 blocks
    roi_pool_kernel<<<grid, 256, 0, stream>>>(input, rois, out);
}